// Round 1
// 106.639 us; speedup vs baseline: 1.0133x; 1.0133x over previous
//
#include <hip/hip_runtime.h>
#include <cmath>
#include <cfloat>

// Problem constants (fixed by setup_inputs: B=4, Q=100, K=17, H=W=128).
constexpr int NB = 4;
constexpr int NQ = 100;
constexpr int NK = 17;
constexpr int NH = 128;
constexpr int NW = 128;

constexpr float HUMAN_CONF = 0.7f;
constexpr float KP_CONF    = 0.5f;
constexpr float NMS_THR    = 0.5f;

// Output layout (flat float32, reference return order):
//   scores  [NB*NQ]          offset 0
//   boxes   [NB*NQ*4]        offset NB*NQ
//   kps     [NB*NQ*NK*3]     offset NB*NQ*5
//   keep    [NB*NQ]          offset NB*NQ*5 + NB*NQ*NK*3
constexpr int OFF_BOXES = NB * NQ;
constexpr int OFF_KPS   = NB * NQ * 5;
constexpr int OFF_KEEP  = NB * NQ * 5 + NB * NQ * NK * 3;

// ---------------- Kernel A: scores + boxes + NMS + compact live-ROI list ----------------
// One block per batch, 128 threads (2 waves). Also zero-fills this batch's kps
// slice (kernel B overwrites live entries only) and emits a compacted list of
// kept boxes with non-empty heatmap ROIs.
__global__ __launch_bounds__(128) void score_nms_kernel(
    const float* __restrict__ logits,   // [NB,NQ,2]
    const float* __restrict__ pboxes,   // [NB,NQ,4] cxcywh in [0,1]
    const int* __restrict__ img_h_p,    // scalar
    const int* __restrict__ img_w_p,    // scalar
    float* __restrict__ out,            // 22800 floats
    int* __restrict__ wcount,           // ws: [NB] live count per batch
    int2* __restrict__ wlist)           // ws: [NB*NQ] (packed x1|y1<<8|x2<<16|y2<<24, gi)
{
    const int b = blockIdx.x;
    const int t = threadIdx.x;

    __shared__ float sbx[NQ][4];          // xyxy image coords, original order
    __shared__ float ssc[NQ];             // softmax max prob
    __shared__ unsigned char sval[NQ];    // valid flag
    __shared__ int   sorder[NQ];          // sorted pos -> original idx
    __shared__ float sortb[NQ][4];        // boxes in sorted order
    __shared__ float sarea[NQ];
    __shared__ unsigned char ssv[NQ];     // valid in sorted order
    __shared__ unsigned long long smask0[NQ], smask1[NQ]; // IoU>thr bitmask per sorted row
    __shared__ unsigned long long skmask[2];              // keep bits (sorted positions)
    __shared__ unsigned long long svb[2];                 // sorted-valid ballot per wave
    __shared__ unsigned long long swl0;                   // wave-0 live ballot

    // Zero-fill this batch's kps slice (NQ*NK*3 = 5100 floats = 1275 float4).
    // Base: OFF_KPS*4 = 8000 B (16B aligned); per-batch stride 20400 B (16B mult).
    {
        float4* kz4 = (float4*)(out + OFF_KPS + b * (NQ * NK * 3));
        const float4 z4 = make_float4(0.0f, 0.0f, 0.0f, 0.0f);
        for (int i = t; i < (NQ * NK * 3) / 4; i += 128) kz4[i] = z4;
    }

    const float iw = (float)img_w_p[0];
    const float ih = (float)img_h_p[0];
    const float sx = (float)NW / iw;      // 0.25 exact for 512
    const float sy = (float)NH / ih;

    if (t < NQ) {
        // softmax over 2 classes; score = max prob, label==0 iff l0 >= l1
        const float l0 = logits[(b * NQ + t) * 2 + 0];
        const float l1 = logits[(b * NQ + t) * 2 + 1];
        const float m  = fmaxf(l0, l1);
        const float e0 = expf(l0 - m);
        const float e1 = expf(l1 - m);
        const float score = fmaxf(e0, e1) / (e0 + e1);
        const bool  lab0  = (l0 >= l1);

        const float cx = pboxes[(b * NQ + t) * 4 + 0];
        const float cy = pboxes[(b * NQ + t) * 4 + 1];
        const float w  = pboxes[(b * NQ + t) * 4 + 2];
        const float h  = pboxes[(b * NQ + t) * 4 + 3];
        sbx[t][0] = (cx - 0.5f * w) * iw;
        sbx[t][1] = (cy - 0.5f * h) * ih;
        sbx[t][2] = (cx + 0.5f * w) * iw;
        sbx[t][3] = (cy + 0.5f * h) * ih;
        ssc[t]  = score;
        sval[t] = (lab0 && score >= HUMAN_CONF) ? 1 : 0;
    }
    __syncthreads();

    // Rank by (key desc, index desc) == reverse of stable ascending argsort.
    if (t < NQ) {
        const float key = sval[t] ? ssc[t] : -INFINITY;
        int rank = 0;
        for (int j = 0; j < NQ; ++j) {
            const float kj = sval[j] ? ssc[j] : -INFINITY;
            if (kj > key || (kj == key && j > t)) rank++;
        }
        sorder[rank] = t;
    }
    __syncthreads();

    if (t < NQ) {
        const int oi = sorder[t];
        const float x1 = sbx[oi][0], y1 = sbx[oi][1], x2 = sbx[oi][2], y2 = sbx[oi][3];
        sortb[t][0] = x1; sortb[t][1] = y1; sortb[t][2] = x2; sortb[t][3] = y2;
        sarea[t] = fmaxf(x2 - x1, 0.0f) * fmaxf(y2 - y1, 0.0f);
        ssv[t]   = sval[oi];
    }
    __syncthreads();

    // Each sorted row t: bitmask over columns j with IoU(t,j) > thr.
    // (Diagonal included: IoU(i,i)=1 > thr for non-degenerate boxes.)
    if (t < NQ) {
        unsigned long long m0 = 0ull, m1 = 0ull;
        const float ax1 = sortb[t][0], ay1 = sortb[t][1], ax2 = sortb[t][2], ay2 = sortb[t][3];
        const float aa = sarea[t];
        for (int j = 0; j < NQ; ++j) {
            const float lx = fmaxf(ax1, sortb[j][0]);
            const float ly = fmaxf(ay1, sortb[j][1]);
            const float rx = fminf(ax2, sortb[j][2]);
            const float ry = fminf(ay2, sortb[j][3]);
            const float wv = fmaxf(rx - lx, 0.0f);
            const float hv = fmaxf(ry - ly, 0.0f);
            const float inter = wv * hv;
            const float uni = aa + sarea[j] - inter;
            const float iou = inter / fmaxf(uni, 1e-9f);
            if (iou > NMS_THR) {
                if (j < 64) m0 |= 1ull << j; else m1 |= 1ull << (j - 64);
            }
        }
        smask0[t] = m0; smask1[t] = m1;
    }

    // Sorted-valid ballot (valid boxes occupy a prefix of sorted order).
    {
        const bool sv = (t < NQ) ? (ssv[t] != 0) : false;
        const unsigned long long vb = __ballot(sv);
        if ((t & 63) == 0) svb[t >> 6] = vb;
    }
    __syncthreads();

    // ffs-driven greedy over bitmasks (thread 0): one iteration per KEPT box
    // (~20) instead of one per valid box (~38). Picking the lowest remaining
    // bit == next unsuppressed box in score order; clearing its whole mask
    // removes everything it suppresses in one step.
    if (t == 0) {
        unsigned long long rem0 = svb[0], rem1 = svb[1];
        unsigned long long k0 = 0ull, k1 = 0ull;
        while (rem0 | rem1) {
            int i;
            unsigned long long bit0 = 0ull, bit1 = 0ull;
            if (rem0) { i = __builtin_ctzll(rem0); bit0 = 1ull << i; }
            else      { const int j = __builtin_ctzll(rem1); i = 64 + j; bit1 = 1ull << j; }
            k0 |= bit0; k1 |= bit1;
            // Clear self explicitly (degenerate zero-area boxes have no diagonal bit).
            rem0 &= ~(smask0[i] | bit0);
            rem1 &= ~(smask1[i] | bit1);
        }
        skmask[0] = k0; skmask[1] = k1;
    }
    __syncthreads();

    // Write scores/boxes/keep outputs + compact live list.
    int  kp = 0, gi = 0;
    int  x1i = 0, y1i = 0, x2i = 0, y2i = 0;
    bool live = false;

    if (t < NQ) {
        const int oi = sorder[t];
        kp = (t < 64) ? (int)((skmask[0] >> t) & 1ull)
                      : (int)((skmask[1] >> (t - 64)) & 1ull);
        gi = b * NQ + oi;

        out[gi] = ssc[oi] * (float)kp;

        const int bi0 = (int)sbx[oi][0];   // trunc toward zero == astype(int32)
        const int bi1 = (int)sbx[oi][1];
        const int bi2 = (int)sbx[oi][2];
        const int bi3 = (int)sbx[oi][3];
        out[OFF_BOXES + gi * 4 + 0] = (float)(bi0 * kp);
        out[OFF_BOXES + gi * 4 + 1] = (float)(bi1 * kp);
        out[OFF_BOXES + gi * 4 + 2] = (float)(bi2 * kp);
        out[OFF_BOXES + gi * 4 + 3] = (float)(bi3 * kp);

        out[OFF_KEEP + gi] = (float)kp;

        // ROI bounds: int * 0.25f exact; trunc toward zero matches astype(int32).
        x1i = max((int)((float)bi0 * sx), 0);
        y1i = max((int)((float)bi1 * sy), 0);
        x2i = min((int)((float)bi2 * sx) + 1, NW);
        y2i = min((int)((float)bi3 * sy) + 1, NH);
        live = kp && (x2i > x1i) && (y2i > y1i);   // empty-ROI kept boxes stay zero
    }

    // Compact live entries: rank = #live threads with smaller t (2-wave prefix).
    const unsigned long long lm = __ballot(live);
    if (t == 0) swl0 = lm;
    __syncthreads();
    if (t == 64) wcount[b] = __popcll(swl0) + __popcll(lm);
    const int lane = t & 63;
    const unsigned long long below = lm & ((lane ? (1ull << lane) : 1ull) - 1ull);
    const int rank = (t < 64) ? __popcll(below) : __popcll(swl0) + __popcll(below);
    if (live) {
        const int pack = x1i | (y1i << 8) | (x2i << 16) | (y2i << 24);  // all in [0,128]
        wlist[b * NQ + rank] = make_int2(pack, gi);
    }
}

// ---------------- Kernel B: ROI keypoint argmax, persistent, one wave per live item ----------------
// Grid = 2048 blocks of 64 threads. Work items are the COMPACTED live
// (box, keypoint) pairs: T = sum_b wcount[b]*NK (~2000 typically). Each block
// grid-strides over items — no dead blocks, 3.3x fewer WG dispatches than the
// previous NB*NQ*NK grid. Batch decode is 3 uniform compares against scalar
// prefix sums (wcount loads are wave-uniform -> s_load).
__global__ __launch_bounds__(64) void kps_kernel(
    const float* __restrict__ hm,       // [NB,NK,NH,NW]
    const int* __restrict__ wcount,     // [NB]
    const int2* __restrict__ wlist,     // [NB*NQ]
    const int* __restrict__ img_h_p,
    const int* __restrict__ img_w_p,
    float* __restrict__ out)
{
    const int c0 = wcount[0] * NK;
    const int c1 = wcount[1] * NK;
    const int c2 = wcount[2] * NK;
    const int c3 = wcount[3] * NK;
    const int t0 = c0, t1 = c0 + c1, t2 = t1 + c2, T = t2 + c3;

    const int lane = threadIdx.x;
    const float sx = (float)NW / (float)img_w_p[0];
    const float sy = (float)NH / (float)img_h_p[0];

    for (int item = blockIdx.x; item < T; item += gridDim.x) {
        int b, base;
        if (item < t1) { if (item < t0) { b = 0; base = 0;  } else { b = 1; base = t0; } }
        else           { if (item < t2) { b = 2; base = t1; } else { b = 3; base = t2; } }
        const int local = item - base;
        const int r = local / NK;            // compile-time-constant divisor -> magic mul
        const int k = local - r * NK;

        const int2 wl = wlist[b * NQ + r];
        const int x1 = wl.x & 255;
        const int y1 = (wl.x >> 8) & 255;
        const int x2 = (wl.x >> 16) & 255;
        const int y2 = (wl.x >> 24) & 255;
        const int gi = wl.y;

        const float4* __restrict__ b4 =
            (const float4*)(hm + (size_t)(b * NK + k) * (NH * NW));   // 64KB-aligned

        const int xa     = x1 & ~3;                     // align ROI left edge down
        const int C4     = (x2 - xa + 3) >> 2;          // float4 chunks per row, 1..32
        const int R      = y2 - y1;
        const int total4 = R * C4;                      // < 2^12
        const unsigned M = (C4 > 1) ? (0xFFFFFFFFu / (unsigned)C4 + 1u) : 0u;

        float best = -INFINITY;
        int   bidx = 0x7fffffff;                        // global flat idx y*NW+x

        auto proc = [&](int idx, float4 v) {
            const int row = (C4 == 1) ? idx : (int)__umulhi((unsigned)idx, M);
            const int xb  = xa + (idx - row * C4) * 4;
            const int g   = (y1 + row) * NW + xb;
            // component order = increasing x = increasing flat idx; strict > keeps
            // the earliest occurrence (argmax tie semantics)
            const float v0 = (xb + 0 >= x1 && xb + 0 < x2) ? v.x : -INFINITY;
            const float v1 = (xb + 1 >= x1 && xb + 1 < x2) ? v.y : -INFINITY;
            const float v2 = (xb + 2 >= x1 && xb + 2 < x2) ? v.z : -INFINITY;
            const float v3 = (xb + 3 < x2) ? v.w : -INFINITY;
            if (v0 > best) { best = v0; bidx = g + 0; }
            if (v1 > best) { best = v1; bidx = g + 1; }
            if (v2 > best) { best = v2; bidx = g + 2; }
            if (v3 > best) { best = v3; bidx = g + 3; }
        };
        auto caddr = [&](int idx) {
            const int row = (C4 == 1) ? idx : (int)__umulhi((unsigned)idx, M);
            return (y1 + row) * (NW / 4) + (xa >> 2) + (idx - row * C4);
        };

        int idx = lane;
        // 4 chunk-loads in flight per iteration (16 values).
        for (; idx + 192 < total4; idx += 256) {
            const int a0 = caddr(idx), a1 = caddr(idx + 64), a2 = caddr(idx + 128), a3 = caddr(idx + 192);
            const float4 v0 = b4[a0];
            const float4 v1 = b4[a1];
            const float4 v2 = b4[a2];
            const float4 v3 = b4[a3];
            proc(idx, v0);
            proc(idx + 64, v1);
            proc(idx + 128, v2);
            proc(idx + 192, v3);
        }
        for (; idx < total4; idx += 64) proc(idx, b4[caddr(idx)]);

        // 64-lane shuffle argmax reduce; tie -> smaller flat index (argmax semantics)
        for (int off = 32; off >= 1; off >>= 1) {
            const float ov = __shfl_down(best, off);
            const int   oi = __shfl_down(bidx, off);
            if (ov > best || (ov == best && oi < bidx)) { best = ov; bidx = oi; }
        }

        if (lane == 0) {
            const int col = bidx & (NW - 1);
            const int row = bidx >> 7;
            float conf = best;
            if (conf < KP_CONF) conf = 0.0f;
            float* kout = out + OFF_KPS + (size_t)gi * (NK * 3) + k * 3;
            kout[0] = (float)col / sx;
            kout[1] = (float)row / sy;
            kout[2] = conf;
        }
    }
}

extern "C" void kernel_launch(void* const* d_in, const int* in_sizes, int n_in,
                              void* d_out, int out_size, void* d_ws, size_t ws_size,
                              hipStream_t stream) {
    const float* logits = (const float*)d_in[0];   // [4,100,2]
    const float* pboxes = (const float*)d_in[1];   // [4,100,4]
    const float* hm     = (const float*)d_in[2];   // [4,17,128,128]
    const int*   img_h  = (const int*)d_in[3];
    const int*   img_w  = (const int*)d_in[4];
    float* out = (float*)d_out;

    int*  wcount = (int*)d_ws;                 // [4]
    int2* wlist  = (int2*)((char*)d_ws + 256); // [400], aligned

    score_nms_kernel<<<NB, 128, 0, stream>>>(logits, pboxes, img_h, img_w, out, wcount, wlist);
    kps_kernel<<<2048, 64, 0, stream>>>(hm, wcount, wlist, img_h, img_w, out);
}